// Round 7
// baseline (264.332 us; speedup 1.0000x reference)
//
#include <hip/hip_runtime.h>
#include <hip/hip_bf16.h>

// Problem constants: B=2, S=2048, D=1024, H=16, DH=64
#define SS 2048
#define DD 1024
#define GK 1024   // GEMM K = D
#define GM 4096   // GEMM M = B*S

// log2(e)/8 : folded into Q projection so attention softmax is exp2(s)
#define QSCALE 0.18033688011112042f

typedef __attribute__((ext_vector_type(8))) short short8;    // 8 bf16 = 4 VGPRs
typedef __attribute__((ext_vector_type(16))) float f32x16;   // 32x32 MFMA C/D

__device__ __forceinline__ short f2bf(float f) {
  union { __hip_bfloat16 h; short s; } u;
  u.h = __float2bfloat16(f);
  return u.s;
}

__device__ __forceinline__ short2 pk2bf(float a, float b) {
  union { __hip_bfloat162 h; short2 s; } u;
  u.h = __float22bfloat162_rn(float2{a, b});
  return u.s;
}

// async global->LDS, 16B per lane; LDS dest = wave-uniform base + lane*16
__device__ __forceinline__ void gld16(const void* g, void* l) {
  __builtin_amdgcn_global_load_lds(
      (const __attribute__((address_space(1))) void*)g,
      (__attribute__((address_space(3))) void*)l, 16, 0, 0);
}

// Tile swizzle: stored chunk c of row r holds source chunk c^(r&7)^((r>>3)&3).
// (r>>3)&3 term: the 4 rows sharing r&7 in a 32-row fragment read hit
// distinct bank groups (round-6 verified: SQ_LDS_BANK_CONFLICT -> 0).
__device__ __forceinline__ int swz(int row, int col) {
  return (col ^ (row & 7) ^ ((row >> 3) & 3)) << 3;
}

// ---------------------------------------------------------------------------
// Fused fp32 -> bf16 convert for 7 arrays (q,k,v + 4 weights)
// ---------------------------------------------------------------------------
struct CvtArgs {
  const float* s[7];
  short* d[7];
  int n8[7];
};

__global__ __launch_bounds__(256) void cvt_all(CvtArgs a) {
  const int y = blockIdx.y;
  const int i = blockIdx.x * 256 + threadIdx.x;
  if (i >= a.n8[y]) return;
  const float4* sp = (const float4*)a.s[y];
  float4 u = sp[2 * i], v = sp[2 * i + 1];
  short8 o;
  short2 p0 = pk2bf(u.x, u.y), p1 = pk2bf(u.z, u.w);
  short2 p2 = pk2bf(v.x, v.y), p3 = pk2bf(v.z, v.w);
  o[0] = p0.x; o[1] = p0.y; o[2] = p1.x; o[3] = p1.y;
  o[4] = p2.x; o[5] = p2.y; o[6] = p3.x; o[7] = p3.y;
  ((short8*)a.d[y])[i] = o;
}

// ---------------------------------------------------------------------------
// Fused QKV projection GEMM (round-5 structure + upgraded swizzle).
// A=X (m=s), B=W (n=feat): epilogue stores are consecutive-lane-contiguous
// (coalesced) even though scalar for z<2. grid (32,8,3) = 3 blocks/CU.
// ---------------------------------------------------------------------------
struct QkvArgs {
  const short* A[3];
  const short* W[3];
  const float* b[3];
  short* out[3];
};

__global__ __launch_bounds__(256, 3) void qkv_gemm(QkvArgs args) {
  const int z = blockIdx.z;
  const short* __restrict__ A = args.A[z];
  const short* __restrict__ W = args.W[z];
  const float* __restrict__ bias = args.b[z];
  short* __restrict__ Cout = args.out[z];

  const int m0 = blockIdx.x * 128;   // s
  const int n0 = blockIdx.y * 128;   // feat
  const int tid = threadIdx.x;
  const int wave = tid >> 6, lane = tid & 63;
  const int l32 = lane & 31, half = lane >> 5;
  const int wrow = (wave >> 1) * 64;
  const int wcol = (wave & 1) * 64;
  const int lxor = (l32 & 7) ^ ((l32 >> 3) & 3);

  __shared__ short Am[128][64];  // [s][k], swizzled, unpadded
  __shared__ short Wm[128][64];  // [feat][k], swizzled, unpadded

  f32x16 acc[2][2];
#pragma unroll
  for (int mb = 0; mb < 2; mb++)
#pragma unroll
    for (int nb = 0; nb < 2; nb++) acc[mb][nb] = (f32x16)0.f;

  for (int k0 = 0; k0 < GK; k0 += 64) {
    __syncthreads();
#pragma unroll
    for (int i = 0; i < 4; i++) {
      int f = wave * 256 + i * 64 + lane;
      int row = f >> 3, col = f & 7;
      int ksw = k0 + swz(row, col);
      gld16(A + (size_t)(m0 + row) * GK + ksw,
            (short*)Am + (size_t)(wave * 256 + i * 64) * 8);
      gld16(W + (size_t)(n0 + row) * GK + ksw,
            (short*)Wm + (size_t)(wave * 256 + i * 64) * 8);
    }
    __syncthreads();
#pragma unroll
    for (int c = 0; c < 4; c++) {
      const int sw = ((2 * c + half) ^ lxor) << 3;
      short8 af[2], bf[2];
#pragma unroll
      for (int mb = 0; mb < 2; mb++) {
        af[mb] = *(const short8*)(&Am[wrow + mb * 32 + l32][0] + sw);
        bf[mb] = *(const short8*)(&Wm[wcol + mb * 32 + l32][0] + sw);
      }
#pragma unroll
      for (int mb = 0; mb < 2; mb++)
#pragma unroll
        for (int nb = 0; nb < 2; nb++)
          acc[mb][nb] = __builtin_amdgcn_mfma_f32_32x32x16_bf16(
              af[mb], bf[nb], acc[mb][nb], 0, 0, 0);
    }
  }

  // Epilogue. C/D: n(lane)=feat, m(regs)=s. Coalesced along feat.
  const float sc = (z == 0) ? QSCALE : 1.0f;
  const int bb = m0 >> 11;
#pragma unroll
  for (int nb = 0; nb < 2; nb++) {
    const int n = n0 + wcol + nb * 32 + l32;
    const float bv = bias[n];
    const int h = n >> 6, d = n & 63;
#pragma unroll
    for (int mb = 0; mb < 2; mb++) {
      const int mbase = m0 + wrow + mb * 32 + 4 * half;
      if (z == 2) {
        // V^T scatter to [B*H][DH][S]; regs 4g..4g+3 = consecutive s
#pragma unroll
        for (int g = 0; g < 4; g++) {
          const int s = (mbase + g * 8) & 2047;
          short2 o0 = pk2bf(acc[mb][nb][4 * g + 0] + bv,
                            acc[mb][nb][4 * g + 1] + bv);
          short2 o1 = pk2bf(acc[mb][nb][4 * g + 2] + bv,
                            acc[mb][nb][4 * g + 3] + bv);
          short4 o = {o0.x, o0.y, o1.x, o1.y};
          *(short4*)&Cout[((size_t)(bb * 16 + h) * 64 + d) * 2048 + s] = o;
        }
      } else {
#pragma unroll
        for (int g = 0; g < 4; g++)
#pragma unroll
          for (int r = 0; r < 4; r++) {
            const int s = (mbase + g * 8 + r) & 2047;
            Cout[((size_t)(bb * 16 + h) * 2048 + s) * 64 + d] =
                f2bf((acc[mb][nb][4 * g + r] + bv) * sc);
          }
      }
    }
  }
}

// ---------------------------------------------------------------------------
// O-projection GEMM (round-5 structure + upgraded swizzle): fp32 out,
// n(lane)=feat -> coalesced scalar float stores. grid (32,16) = 2 blocks/CU.
// ---------------------------------------------------------------------------
__global__ __launch_bounds__(256) void gemm_o(
    const short* __restrict__ A, const short* __restrict__ W,
    const float* __restrict__ bias, float* __restrict__ Cout) {
  const int m0 = blockIdx.x * 128;  // s
  const int n0 = blockIdx.y * 64;   // feat
  const int tid = threadIdx.x;
  const int wave = tid >> 6, lane = tid & 63;
  const int l32 = lane & 31, half = lane >> 5;
  const int lxor = (l32 & 7) ^ ((l32 >> 3) & 3);

  __shared__ short Am[128][64];
  __shared__ short Wm[64][64];

  f32x16 acc[2];
  acc[0] = (f32x16)0.f;
  acc[1] = (f32x16)0.f;

  for (int k0 = 0; k0 < GK; k0 += 64) {
    __syncthreads();
#pragma unroll
    for (int i = 0; i < 4; i++) {
      int f = wave * 256 + i * 64 + lane;
      int row = f >> 3, col = f & 7;
      gld16(A + (size_t)(m0 + row) * GK + k0 + swz(row, col),
            (short*)Am + (size_t)(wave * 256 + i * 64) * 8);
    }
#pragma unroll
    for (int i = 0; i < 2; i++) {
      int f = wave * 128 + i * 64 + lane;
      int row = f >> 3, col = f & 7;
      gld16(W + (size_t)(n0 + row) * GK + k0 + swz(row, col),
            (short*)Wm + (size_t)(wave * 128 + i * 64) * 8);
    }
    __syncthreads();
#pragma unroll
    for (int c = 0; c < 4; c++) {
      const int sw = ((2 * c + half) ^ lxor) << 3;
      short8 af = *(const short8*)(&Am[wave * 32 + l32][0] + sw);
      short8 bf[2];
#pragma unroll
      for (int nb = 0; nb < 2; nb++)
        bf[nb] = *(const short8*)(&Wm[nb * 32 + l32][0] + sw);
#pragma unroll
      for (int nb = 0; nb < 2; nb++)
        acc[nb] = __builtin_amdgcn_mfma_f32_32x32x16_bf16(
            af, bf[nb], acc[nb], 0, 0, 0);
    }
  }

  // n(lane)=feat -> coalesced scalar stores
#pragma unroll
  for (int nb = 0; nb < 2; nb++) {
    const int n = n0 + nb * 32 + l32;
    const float bv = bias[n];
    const int mbase = m0 + wave * 32 + 4 * half;
#pragma unroll
    for (int g = 0; g < 4; g++)
#pragma unroll
      for (int r = 0; r < 4; r++)
        Cout[(size_t)(mbase + g * 8 + r) * DD + n] = acc[nb][4 * g + r] + bv;
  }
}

// ---------------------------------------------------------------------------
// Flash attention, 8 waves / 512 threads per block (4 waves/SIMD for
// MFMA<->VALU phase overlap). Wave pair (w, w+4) shares q-range (w&3)*32
// and splits each 64-kk tile into halves (kksel = wave>>2). Per wave per
// kt: 4 S-MFMA + 16 exp + tree + 4 PV-MFMA. Partial O/l merged once at
// the end through LDS aliased over the dead K/V buffers.
// ---------------------------------------------------------------------------
union FlashSmem {
  struct {
    short Ks[2][64][64];   // [kk][d], swizzled (16 KB)
    short Vs[2][64][64];   // [d][kk], swizzled (16 KB)
    short Ps[8][32][36];   // per-wave [q][kk-half] (18 KB)
  } m;
  struct {                 // epilogue overlay (K/V/P dead)
    float Opart[4][64][34];
    float lpart[4][64];
  } e;
};

__global__ __launch_bounds__(512, 4) void flash_mfma(
    const short* __restrict__ qh, const short* __restrict__ kh,
    const short* __restrict__ vt, short* __restrict__ ao) {
  const int bh = blockIdx.y;
  const int q0 = blockIdx.x * 128;
  const int tid = threadIdx.x;
  const int wave = tid >> 6, lane = tid & 63;
  const int l32 = lane & 31, half = lane >> 5;
  const int lxor = (l32 & 7) ^ ((l32 >> 3) & 3);
  const int qsel = wave & 3;   // q subgroup
  const int kksel = wave >> 2; // kk half of each tile

  __shared__ FlashSmem sm;

  // Q B-fragments from global: q = l32, chunk c: d = c*16 + half*8
  short8 qf[4];
#pragma unroll
  for (int c = 0; c < 4; c++)
    qf[c] = *(const short8*)(
        qh + ((size_t)bh * SS + q0 + qsel * 32 + l32) * 64 + c * 16 + half * 8);

  f32x16 o[2];
  o[0] = (f32x16)0.f;
  o[1] = (f32x16)0.f;
  float l_part = 0.f;

  // 512 threads stage one 16B K-chunk + one 16B V-chunk each (512 chunks/tile)
  auto stage = [&](int buf, int kt) {
    int row = tid >> 3, col = tid & 7;
    int sw = swz(row, col);
    gld16(kh + ((size_t)bh * SS + kt * 64 + row) * 64 + sw,
          (short*)sm.m.Ks + (size_t)buf * 4096 + (size_t)(wave * 64) * 8);
    gld16(vt + ((size_t)bh * 64 + row) * SS + kt * 64 + sw,
          (short*)sm.m.Vs + (size_t)buf * 4096 + (size_t)(wave * 64) * 8);
  };

  stage(0, 0);
  __syncthreads();

  for (int kt = 0; kt < 32; kt++) {
    const int cur = kt & 1;
    if (kt < 31) stage(1 - cur, kt + 1);  // async prefetch, drained by barrier

    // S^T = K_half · Q^T : m = kk (32 of this wave's half), n = q
    f32x16 s = (f32x16)0.f;
#pragma unroll
    for (int c = 0; c < 4; c++) {
      const int sw = ((2 * c + half) ^ lxor) << 3;
      short8 kf = *(const short8*)(&sm.m.Ks[cur][kksel * 32 + l32][0] + sw);
      s = __builtin_amdgcn_mfma_f32_32x32x16_bf16(kf, qf[c], s, 0, 0, 0);
    }

    // p = exp2(s); per-lane partial l via register tree (no shuffles)
#pragma unroll
    for (int r = 0; r < 16; r++) s[r] = __builtin_amdgcn_exp2f(s[r]);
    {
      float t[16];
#pragma unroll
      for (int r = 0; r < 16; r++) t[r] = s[r];
#pragma unroll
      for (int st = 8; st > 0; st >>= 1)
#pragma unroll
        for (int r = 0; r < st; r++) t[r] += t[r + st];
      l_part += t[0];
    }

    // P^T -> wave-private LDS [q][kk-half]
#pragma unroll
    for (int g = 0; g < 4; g++) {
      short2 p0 = pk2bf(s[4 * g + 0], s[4 * g + 1]);
      short2 p1 = pk2bf(s[4 * g + 2], s[4 * g + 3]);
      short4 pk = {p0.x, p0.y, p1.x, p1.y};
      *(short4*)&sm.m.Ps[wave][l32][g * 8 + half * 4] = pk;
    }

    // O^T += V^T_half · P^T : m = d (2 blocks), k = 32 kk of this half
#pragma unroll
    for (int c = 0; c < 2; c++) {
      short8 pf = *(const short8*)&sm.m.Ps[wave][l32][c * 16 + half * 8];
      const int chunk = kksel * 4 + c * 2 + half;  // kk 16B-chunk in [0,8)
      const int sw2 = (chunk ^ lxor) << 3;
#pragma unroll
      for (int mb = 0; mb < 2; mb++) {
        short8 vf = *(const short8*)(&sm.m.Vs[cur][mb * 32 + l32][0] + sw2);
        o[mb] = __builtin_amdgcn_mfma_f32_32x32x16_bf16(vf, pf, o[mb], 0, 0, 0);
      }
    }

    __syncthreads();  // drains prefetch + guards buffer swap
  }

  // Merge wave-pair partials through LDS (aliased over dead K/V buffers).
  const float l_half = l_part + __shfl_xor(l_part, 32);
  if (wave >= 4) {
    const int w = wave - 4;
#pragma unroll
    for (int mb = 0; mb < 2; mb++)
#pragma unroll
      for (int r = 0; r < 16; r++)
        sm.e.Opart[w][lane][mb * 16 + r] = o[mb][r];
    sm.e.lpart[w][lane] = l_half;
  }
  __syncthreads();
  if (wave < 4) {
#pragma unroll
    for (int mb = 0; mb < 2; mb++)
#pragma unroll
      for (int r = 0; r < 16; r++)
        o[mb][r] += sm.e.Opart[wave][lane][mb * 16 + r];
    const float inv = 1.0f / (l_half + sm.e.lpart[wave][lane]);
    const int b = bh >> 4, h = bh & 15;
    const int q = q0 + qsel * 32 + l32;
#pragma unroll
    for (int mb = 0; mb < 2; mb++)
#pragma unroll
      for (int g = 0; g < 4; g++) {
        const int d = mb * 32 + g * 8 + half * 4;
        short2 o0 = pk2bf(o[mb][4 * g + 0] * inv, o[mb][4 * g + 1] * inv);
        short2 o1 = pk2bf(o[mb][4 * g + 2] * inv, o[mb][4 * g + 3] * inv);
        short4 ok = {o0.x, o0.y, o1.x, o1.y};
        *(short4*)&ao[((size_t)b * SS + q) * DD + h * 64 + d] = ok;
      }
  }
}

// ---------------------------------------------------------------------------
extern "C" void kernel_launch(void* const* d_in, const int* in_sizes, int n_in,
                              void* d_out, int out_size, void* d_ws,
                              size_t ws_size, hipStream_t stream) {
  const float* q = (const float*)d_in[0];
  const float* k = (const float*)d_in[1];
  const float* v = (const float*)d_in[2];
  const float* Wq = (const float*)d_in[3];
  const float* bq = (const float*)d_in[4];
  const float* Wk = (const float*)d_in[5];
  const float* bk = (const float*)d_in[6];
  const float* Wv = (const float*)d_in[7];
  const float* bv = (const float*)d_in[8];
  const float* Wo = (const float*)d_in[9];
  const float* bo = (const float*)d_in[10];
  float* out = (float*)d_out;

  const size_t MEG = 1024 * 1024;
  short* wsb = (short*)d_ws;
  short* Wqb = wsb + 0 * MEG;
  short* Wkb = wsb + 1 * MEG;
  short* Wvb = wsb + 2 * MEG;
  short* Wob = wsb + 3 * MEG;
  short* qb = wsb + 4 * MEG;    // bf16 copies of q,k,v: 4M each
  short* kb = wsb + 8 * MEG;
  short* vb = wsb + 12 * MEG;
  short* qhp = wsb + 16 * MEG;  // [B*H][S][DH] (pre-scaled by log2e/8)
  short* khp = wsb + 20 * MEG;  // [B*H][S][DH]
  short* vtp = wsb + 24 * MEG;  // [B*H][DH][S]
  short* aop = wsb + 28 * MEG;  // [B,S,D]

  CvtArgs ca;
  ca.s[0] = q;  ca.d[0] = qb;  ca.n8[0] = 524288;
  ca.s[1] = k;  ca.d[1] = kb;  ca.n8[1] = 524288;
  ca.s[2] = v;  ca.d[2] = vb;  ca.n8[2] = 524288;
  ca.s[3] = Wq; ca.d[3] = Wqb; ca.n8[3] = 131072;
  ca.s[4] = Wk; ca.d[4] = Wkb; ca.n8[4] = 131072;
  ca.s[5] = Wv; ca.d[5] = Wvb; ca.n8[5] = 131072;
  ca.s[6] = Wo; ca.d[6] = Wob; ca.n8[6] = 131072;
  cvt_all<<<dim3(2048, 7), 256, 0, stream>>>(ca);

  QkvArgs qa;
  qa.A[0] = qb; qa.W[0] = Wqb; qa.b[0] = bq; qa.out[0] = qhp;
  qa.A[1] = kb; qa.W[1] = Wkb; qa.b[1] = bk; qa.out[1] = khp;
  qa.A[2] = vb; qa.W[2] = Wvb; qa.b[2] = bv; qa.out[2] = vtp;
  qkv_gemm<<<dim3(GM / 128, DD / 128, 3), 256, 0, stream>>>(qa);

  flash_mfma<<<dim3(SS / 128, 32), 512, 0, stream>>>(qhp, khp, vtp, aop);

  gemm_o<<<dim3(GM / 128, DD / 64), 256, 0, stream>>>(aop, Wob, bo, out);
}

// Round 8
// 230.281 us; speedup vs baseline: 1.1479x; 1.1479x over previous
//
#include <hip/hip_runtime.h>
#include <hip/hip_bf16.h>

// Problem constants: B=2, S=2048, D=1024, H=16, DH=64
#define SS 2048
#define DD 1024
#define GK 1024   // GEMM K = D
#define GM 4096   // GEMM M = B*S

// log2(e)/8 : folded into Q projection so attention softmax is exp2(s)
#define QSCALE 0.18033688011112042f

typedef __attribute__((ext_vector_type(8))) short short8;    // 8 bf16 = 4 VGPRs
typedef __attribute__((ext_vector_type(16))) float f32x16;   // 32x32 MFMA C/D

__device__ __forceinline__ short f2bf(float f) {
  union { __hip_bfloat16 h; short s; } u;
  u.h = __float2bfloat16(f);
  return u.s;
}

__device__ __forceinline__ short2 pk2bf(float a, float b) {
  union { __hip_bfloat162 h; short2 s; } u;
  u.h = __float22bfloat162_rn(float2{a, b});
  return u.s;
}

// async global->LDS, 16B per lane; LDS dest = wave-uniform base + lane*16
__device__ __forceinline__ void gld16(const void* g, void* l) {
  __builtin_amdgcn_global_load_lds(
      (const __attribute__((address_space(1))) void*)g,
      (__attribute__((address_space(3))) void*)l, 16, 0, 0);
}

// Tile swizzle: stored chunk c of row r holds source chunk c^(r&7)^((r>>3)&3).
// (r>>3)&3 term: the 4 rows sharing r&7 in a 32-row fragment read hit
// distinct bank groups (round-6 verified: SQ_LDS_BANK_CONFLICT -> 0).
__device__ __forceinline__ int swz(int row, int col) {
  return (col ^ (row & 7) ^ ((row >> 3) & 3)) << 3;
}

// ---------------------------------------------------------------------------
// Fused fp32 -> bf16 convert for 7 arrays (q,k,v + 4 weights)
// ---------------------------------------------------------------------------
struct CvtArgs {
  const float* s[7];
  short* d[7];
  int n8[7];
};

__global__ __launch_bounds__(256) void cvt_all(CvtArgs a) {
  const int y = blockIdx.y;
  const int i = blockIdx.x * 256 + threadIdx.x;
  if (i >= a.n8[y]) return;
  const float4* sp = (const float4*)a.s[y];
  float4 u = sp[2 * i], v = sp[2 * i + 1];
  short8 o;
  short2 p0 = pk2bf(u.x, u.y), p1 = pk2bf(u.z, u.w);
  short2 p2 = pk2bf(v.x, v.y), p3 = pk2bf(v.z, v.w);
  o[0] = p0.x; o[1] = p0.y; o[2] = p1.x; o[3] = p1.y;
  o[4] = p2.x; o[5] = p2.y; o[6] = p3.x; o[7] = p3.y;
  ((short8*)a.d[y])[i] = o;
}

// ---------------------------------------------------------------------------
// Fused QKV projection GEMM. A=X (m=s), B=W (n=feat): epilogue stores are
// consecutive-lane-contiguous (coalesced). grid (32,8,3) = 3 blocks/CU.
// ---------------------------------------------------------------------------
struct QkvArgs {
  const short* A[3];
  const short* W[3];
  const float* b[3];
  short* out[3];
};

__global__ __launch_bounds__(256, 3) void qkv_gemm(QkvArgs args) {
  const int z = blockIdx.z;
  const short* __restrict__ A = args.A[z];
  const short* __restrict__ W = args.W[z];
  const float* __restrict__ bias = args.b[z];
  short* __restrict__ Cout = args.out[z];

  const int m0 = blockIdx.x * 128;   // s
  const int n0 = blockIdx.y * 128;   // feat
  const int tid = threadIdx.x;
  const int wave = tid >> 6, lane = tid & 63;
  const int l32 = lane & 31, half = lane >> 5;
  const int wrow = (wave >> 1) * 64;
  const int wcol = (wave & 1) * 64;
  const int lxor = (l32 & 7) ^ ((l32 >> 3) & 3);

  __shared__ short Am[128][64];  // [s][k], swizzled, unpadded
  __shared__ short Wm[128][64];  // [feat][k], swizzled, unpadded

  f32x16 acc[2][2];
#pragma unroll
  for (int mb = 0; mb < 2; mb++)
#pragma unroll
    for (int nb = 0; nb < 2; nb++) acc[mb][nb] = (f32x16)0.f;

  for (int k0 = 0; k0 < GK; k0 += 64) {
    __syncthreads();
#pragma unroll
    for (int i = 0; i < 4; i++) {
      int f = wave * 256 + i * 64 + lane;
      int row = f >> 3, col = f & 7;
      int ksw = k0 + swz(row, col);
      gld16(A + (size_t)(m0 + row) * GK + ksw,
            (short*)Am + (size_t)(wave * 256 + i * 64) * 8);
      gld16(W + (size_t)(n0 + row) * GK + ksw,
            (short*)Wm + (size_t)(wave * 256 + i * 64) * 8);
    }
    __syncthreads();
#pragma unroll
    for (int c = 0; c < 4; c++) {
      const int sw = ((2 * c + half) ^ lxor) << 3;
      short8 af[2], bf[2];
#pragma unroll
      for (int mb = 0; mb < 2; mb++) {
        af[mb] = *(const short8*)(&Am[wrow + mb * 32 + l32][0] + sw);
        bf[mb] = *(const short8*)(&Wm[wcol + mb * 32 + l32][0] + sw);
      }
#pragma unroll
      for (int mb = 0; mb < 2; mb++)
#pragma unroll
        for (int nb = 0; nb < 2; nb++)
          acc[mb][nb] = __builtin_amdgcn_mfma_f32_32x32x16_bf16(
              af[mb], bf[nb], acc[mb][nb], 0, 0, 0);
    }
  }

  // Epilogue. C/D: n(lane)=feat, m(regs)=s. Coalesced along feat.
  const float sc = (z == 0) ? QSCALE : 1.0f;
  const int bb = m0 >> 11;
#pragma unroll
  for (int nb = 0; nb < 2; nb++) {
    const int n = n0 + wcol + nb * 32 + l32;
    const float bv = bias[n];
    const int h = n >> 6, d = n & 63;
#pragma unroll
    for (int mb = 0; mb < 2; mb++) {
      const int mbase = m0 + wrow + mb * 32 + 4 * half;
      if (z == 2) {
        // V^T scatter to [B*H][DH][S]; regs 4g..4g+3 = consecutive s
#pragma unroll
        for (int g = 0; g < 4; g++) {
          const int s = (mbase + g * 8) & 2047;
          short2 o0 = pk2bf(acc[mb][nb][4 * g + 0] + bv,
                            acc[mb][nb][4 * g + 1] + bv);
          short2 o1 = pk2bf(acc[mb][nb][4 * g + 2] + bv,
                            acc[mb][nb][4 * g + 3] + bv);
          short4 o = {o0.x, o0.y, o1.x, o1.y};
          *(short4*)&Cout[((size_t)(bb * 16 + h) * 64 + d) * 2048 + s] = o;
        }
      } else {
#pragma unroll
        for (int g = 0; g < 4; g++)
#pragma unroll
          for (int r = 0; r < 4; r++) {
            const int s = (mbase + g * 8 + r) & 2047;
            Cout[((size_t)(bb * 16 + h) * 2048 + s) * 64 + d] =
                f2bf((acc[mb][nb][4 * g + r] + bv) * sc);
          }
      }
    }
  }
}

// ---------------------------------------------------------------------------
// O-projection GEMM: fp32 out, n(lane)=feat -> coalesced scalar float
// stores. grid (32,16) = 512 = 2 blocks/CU.
// ---------------------------------------------------------------------------
__global__ __launch_bounds__(256) void gemm_o(
    const short* __restrict__ A, const short* __restrict__ W,
    const float* __restrict__ bias, float* __restrict__ Cout) {
  const int m0 = blockIdx.x * 128;  // s
  const int n0 = blockIdx.y * 64;   // feat
  const int tid = threadIdx.x;
  const int wave = tid >> 6, lane = tid & 63;
  const int l32 = lane & 31, half = lane >> 5;
  const int lxor = (l32 & 7) ^ ((l32 >> 3) & 3);

  __shared__ short Am[128][64];
  __shared__ short Wm[64][64];

  f32x16 acc[2];
  acc[0] = (f32x16)0.f;
  acc[1] = (f32x16)0.f;

  for (int k0 = 0; k0 < GK; k0 += 64) {
    __syncthreads();
#pragma unroll
    for (int i = 0; i < 4; i++) {
      int f = wave * 256 + i * 64 + lane;
      int row = f >> 3, col = f & 7;
      gld16(A + (size_t)(m0 + row) * GK + k0 + swz(row, col),
            (short*)Am + (size_t)(wave * 256 + i * 64) * 8);
    }
#pragma unroll
    for (int i = 0; i < 2; i++) {
      int f = wave * 128 + i * 64 + lane;
      int row = f >> 3, col = f & 7;
      gld16(W + (size_t)(n0 + row) * GK + k0 + swz(row, col),
            (short*)Wm + (size_t)(wave * 128 + i * 64) * 8);
    }
    __syncthreads();
#pragma unroll
    for (int c = 0; c < 4; c++) {
      const int sw = ((2 * c + half) ^ lxor) << 3;
      short8 af = *(const short8*)(&Am[wave * 32 + l32][0] + sw);
      short8 bf[2];
#pragma unroll
      for (int nb = 0; nb < 2; nb++)
        bf[nb] = *(const short8*)(&Wm[nb * 32 + l32][0] + sw);
#pragma unroll
      for (int nb = 0; nb < 2; nb++)
        acc[nb] = __builtin_amdgcn_mfma_f32_32x32x16_bf16(
            af, bf[nb], acc[nb], 0, 0, 0);
    }
  }

  // n(lane)=feat -> coalesced scalar stores
#pragma unroll
  for (int nb = 0; nb < 2; nb++) {
    const int n = n0 + nb * 32 + l32;
    const float bv = bias[n];
    const int mbase = m0 + wave * 32 + 4 * half;
#pragma unroll
    for (int g = 0; g < 4; g++)
#pragma unroll
      for (int r = 0; r < 4; r++)
        Cout[(size_t)(mbase + g * 8 + r) * DD + n] = acc[nb][4 * g + r] + bv;
  }
}

// ---------------------------------------------------------------------------
// Flash attention: round-5 structure (best measured) + round-6 swizzle
// (conflicts -> 0). 256 threads, 4 waves x 32 q. 32x32x16 MFMA.
// S^T = K·Q^T (m=kk 2x32, n=q); O^T += V^T·P^T (m=d 2x32, n=q).
// l-sum: per-lane register pairwise tree + single shfl_xor(32) at end
// (round-6 lacc-MFMA variant was a net loss: matrix pipe +25%).
// K/V double-buffered via global_load_lds, one barrier per k-tile.
// ---------------------------------------------------------------------------
__global__ __launch_bounds__(256) void flash_mfma(
    const short* __restrict__ qh, const short* __restrict__ kh,
    const short* __restrict__ vt, short* __restrict__ ao) {
  const int bh = blockIdx.y;
  const int q0 = blockIdx.x * 128;
  const int tid = threadIdx.x;
  const int wave = tid >> 6, lane = tid & 63;
  const int l32 = lane & 31, half = lane >> 5;
  const int lxor = (l32 & 7) ^ ((l32 >> 3) & 3);

  __shared__ short Ks[2][64][64];   // [kk][d], swizzled
  __shared__ short Vs[2][64][64];   // [d][kk], swizzled
  __shared__ short Ps[4][32][68];   // per-wave [q][kk], pad 68 (2-way max)

  // Q B-fragments from global: q = l32, chunk c: d = c*16 + half*8
  short8 qf[4];
#pragma unroll
  for (int c = 0; c < 4; c++)
    qf[c] = *(const short8*)(
        qh + ((size_t)bh * SS + q0 + wave * 32 + l32) * 64 + c * 16 + half * 8);

  f32x16 o[2];
  o[0] = (f32x16)0.f;
  o[1] = (f32x16)0.f;
  float l_part = 0.f;

  auto stage = [&](int buf, int kt) {
#pragma unroll
    for (int i = 0; i < 2; i++) {
      int f = wave * 128 + i * 64 + lane;
      int row = f >> 3, col = f & 7;
      int sw = swz(row, col);
      gld16(kh + ((size_t)bh * SS + kt * 64 + row) * 64 + sw,
            (short*)Ks + (size_t)buf * 4096 + (size_t)(wave * 128 + i * 64) * 8);
      gld16(vt + ((size_t)bh * 64 + row) * SS + kt * 64 + sw,
            (short*)Vs + (size_t)buf * 4096 + (size_t)(wave * 128 + i * 64) * 8);
    }
  };

  stage(0, 0);
  __syncthreads();

  for (int kt = 0; kt < 32; kt++) {
    const int cur = kt & 1;
    if (kt < 31) stage(1 - cur, kt + 1);  // async prefetch, drained by barrier

    // S^T = K · Q^T : m = kk (2 blocks), n = q
    f32x16 s[2];
    s[0] = (f32x16)0.f;
    s[1] = (f32x16)0.f;
#pragma unroll
    for (int c = 0; c < 4; c++) {
      const int sw = ((2 * c + half) ^ lxor) << 3;
      short8 kf[2];
#pragma unroll
      for (int mb = 0; mb < 2; mb++)
        kf[mb] = *(const short8*)(&Ks[cur][mb * 32 + l32][0] + sw);
#pragma unroll
      for (int mb = 0; mb < 2; mb++)
        s[mb] = __builtin_amdgcn_mfma_f32_32x32x16_bf16(
            kf[mb], qf[c], s[mb], 0, 0, 0);
    }

    // p = exp2(s); per-lane partial l via register pairwise tree
#pragma unroll
    for (int mb = 0; mb < 2; mb++)
#pragma unroll
      for (int r = 0; r < 16; r++)
        s[mb][r] = __builtin_amdgcn_exp2f(s[mb][r]);
    {
      float t[16];
#pragma unroll
      for (int r = 0; r < 16; r++) t[r] = s[0][r] + s[1][r];
#pragma unroll
      for (int st = 8; st > 0; st >>= 1)
#pragma unroll
        for (int r = 0; r < st; r++) t[r] += t[r + st];
      l_part += t[0];
    }

    // P^T -> wave-private LDS [q][kk]; regs 4g..4g+3 = consecutive kk
#pragma unroll
    for (int mb = 0; mb < 2; mb++)
#pragma unroll
      for (int g = 0; g < 4; g++) {
        short2 p0 = pk2bf(s[mb][4 * g + 0], s[mb][4 * g + 1]);
        short2 p1 = pk2bf(s[mb][4 * g + 2], s[mb][4 * g + 3]);
        short4 pk = {p0.x, p0.y, p1.x, p1.y};
        *(short4*)&Ps[wave][l32][mb * 32 + g * 8 + half * 4] = pk;
      }

    // O^T += V^T · P^T : m = d (2 blocks), n = q, k = kk
#pragma unroll
    for (int c = 0; c < 4; c++) {
      const int sw = ((2 * c + half) ^ lxor) << 3;
      short8 vf[2];
#pragma unroll
      for (int mb = 0; mb < 2; mb++)
        vf[mb] = *(const short8*)(&Vs[cur][mb * 32 + l32][0] + sw);
      short8 pf = *(const short8*)&Ps[wave][l32][c * 16 + half * 8];
#pragma unroll
      for (int mb = 0; mb < 2; mb++)
        o[mb] = __builtin_amdgcn_mfma_f32_32x32x16_bf16(
            vf[mb], pf, o[mb], 0, 0, 0);
    }

    __syncthreads();  // drains prefetch + guards buffer swap
  }

  // Epilogue: l across halves via one shuffle; O^T n=q, m=d.
  const float l_tot = l_part + __shfl_xor(l_part, 32);
  const float inv = 1.0f / l_tot;
  const int b = bh >> 4, h = bh & 15;
  const int q = q0 + wave * 32 + l32;
#pragma unroll
  for (int mb = 0; mb < 2; mb++)
#pragma unroll
    for (int g = 0; g < 4; g++) {
      const int d = mb * 32 + g * 8 + half * 4;
      short2 o0 = pk2bf(o[mb][4 * g + 0] * inv, o[mb][4 * g + 1] * inv);
      short2 o1 = pk2bf(o[mb][4 * g + 2] * inv, o[mb][4 * g + 3] * inv);
      short4 ok = {o0.x, o0.y, o1.x, o1.y};
      *(short4*)&ao[((size_t)b * SS + q) * DD + h * 64 + d] = ok;
    }
}

// ---------------------------------------------------------------------------
extern "C" void kernel_launch(void* const* d_in, const int* in_sizes, int n_in,
                              void* d_out, int out_size, void* d_ws,
                              size_t ws_size, hipStream_t stream) {
  const float* q = (const float*)d_in[0];
  const float* k = (const float*)d_in[1];
  const float* v = (const float*)d_in[2];
  const float* Wq = (const float*)d_in[3];
  const float* bq = (const float*)d_in[4];
  const float* Wk = (const float*)d_in[5];
  const float* bk = (const float*)d_in[6];
  const float* Wv = (const float*)d_in[7];
  const float* bv = (const float*)d_in[8];
  const float* Wo = (const float*)d_in[9];
  const float* bo = (const float*)d_in[10];
  float* out = (float*)d_out;

  const size_t MEG = 1024 * 1024;
  short* wsb = (short*)d_ws;
  short* Wqb = wsb + 0 * MEG;
  short* Wkb = wsb + 1 * MEG;
  short* Wvb = wsb + 2 * MEG;
  short* Wob = wsb + 3 * MEG;
  short* qb = wsb + 4 * MEG;    // bf16 copies of q,k,v: 4M each
  short* kb = wsb + 8 * MEG;
  short* vb = wsb + 12 * MEG;
  short* qhp = wsb + 16 * MEG;  // [B*H][S][DH] (pre-scaled by log2e/8)
  short* khp = wsb + 20 * MEG;  // [B*H][S][DH]
  short* vtp = wsb + 24 * MEG;  // [B*H][DH][S]
  short* aop = wsb + 28 * MEG;  // [B,S,D]

  CvtArgs ca;
  ca.s[0] = q;  ca.d[0] = qb;  ca.n8[0] = 524288;
  ca.s[1] = k;  ca.d[1] = kb;  ca.n8[1] = 524288;
  ca.s[2] = v;  ca.d[2] = vb;  ca.n8[2] = 524288;
  ca.s[3] = Wq; ca.d[3] = Wqb; ca.n8[3] = 131072;
  ca.s[4] = Wk; ca.d[4] = Wkb; ca.n8[4] = 131072;
  ca.s[5] = Wv; ca.d[5] = Wvb; ca.n8[5] = 131072;
  ca.s[6] = Wo; ca.d[6] = Wob; ca.n8[6] = 131072;
  cvt_all<<<dim3(2048, 7), 256, 0, stream>>>(ca);

  QkvArgs qa;
  qa.A[0] = qb; qa.W[0] = Wqb; qa.b[0] = bq; qa.out[0] = qhp;
  qa.A[1] = kb; qa.W[1] = Wkb; qa.b[1] = bk; qa.out[1] = khp;
  qa.A[2] = vb; qa.W[2] = Wvb; qa.b[2] = bv; qa.out[2] = vtp;
  qkv_gemm<<<dim3(GM / 128, DD / 128, 3), 256, 0, stream>>>(qa);

  flash_mfma<<<dim3(SS / 128, 32), 256, 0, stream>>>(qhp, khp, vtp, aop);

  gemm_o<<<dim3(GM / 128, DD / 64), 256, 0, stream>>>(aop, Wob, bo, out);
}

// Round 9
// 217.397 us; speedup vs baseline: 1.2159x; 1.0593x over previous
//
#include <hip/hip_runtime.h>
#include <hip/hip_bf16.h>

// Problem constants: B=2, S=2048, D=1024, H=16, DH=64
#define SS 2048
#define DD 1024
#define GK 1024   // GEMM K = D
#define GM 4096   // GEMM M = B*S

// log2(e)/8 : folded into Q projection so attention softmax is exp2(s)
#define QSCALE 0.18033688011112042f

typedef __attribute__((ext_vector_type(8))) short short8;    // 8 bf16 = 4 VGPRs
typedef __attribute__((ext_vector_type(16))) float f32x16;   // 32x32 MFMA C/D

__device__ __forceinline__ short f2bf(float f) {
  union { __hip_bfloat16 h; short s; } u;
  u.h = __float2bfloat16(f);
  return u.s;
}

__device__ __forceinline__ short2 pk2bf(float a, float b) {
  union { __hip_bfloat162 h; short2 s; } u;
  u.h = __float22bfloat162_rn(float2{a, b});
  return u.s;
}

// async global->LDS, 16B per lane; LDS dest = wave-uniform base + lane*16
__device__ __forceinline__ void gld16(const void* g, void* l) {
  __builtin_amdgcn_global_load_lds(
      (const __attribute__((address_space(1))) void*)g,
      (__attribute__((address_space(3))) void*)l, 16, 0, 0);
}

// Tile swizzle: stored chunk c of row r holds source chunk c^(r&7)^((r>>3)&3).
// (r>>3)&3 term: the 4 rows sharing r&7 in a 32-row fragment read hit
// distinct bank groups (round-6 verified: SQ_LDS_BANK_CONFLICT -> 0).
// Works for 8-chunk (64-col) and 16-chunk (128-col) rows alike.
__device__ __forceinline__ int swz(int row, int col) {
  return (col ^ (row & 7) ^ ((row >> 3) & 3)) << 3;
}

// ---------------------------------------------------------------------------
// Fused fp32 -> bf16 convert for 7 arrays (q,k,v + 4 weights)
// ---------------------------------------------------------------------------
struct CvtArgs {
  const float* s[7];
  short* d[7];
  int n8[7];
};

__global__ __launch_bounds__(256) void cvt_all(CvtArgs a) {
  const int y = blockIdx.y;
  const int i = blockIdx.x * 256 + threadIdx.x;
  if (i >= a.n8[y]) return;
  const float4* sp = (const float4*)a.s[y];
  float4 u = sp[2 * i], v = sp[2 * i + 1];
  short8 o;
  short2 p0 = pk2bf(u.x, u.y), p1 = pk2bf(u.z, u.w);
  short2 p2 = pk2bf(v.x, v.y), p3 = pk2bf(v.z, v.w);
  o[0] = p0.x; o[1] = p0.y; o[2] = p1.x; o[3] = p1.y;
  o[4] = p2.x; o[5] = p2.y; o[6] = p3.x; o[7] = p3.y;
  ((short8*)a.d[y])[i] = o;
}

// ---------------------------------------------------------------------------
// Fused QKV projection GEMM. A=X (m=s), B=W (n=feat): epilogue stores are
// consecutive-lane-contiguous (coalesced). grid (32,8,3) = 3 blocks/CU.
// ---------------------------------------------------------------------------
struct QkvArgs {
  const short* A[3];
  const short* W[3];
  const float* b[3];
  short* out[3];
};

__global__ __launch_bounds__(256, 3) void qkv_gemm(QkvArgs args) {
  const int z = blockIdx.z;
  const short* __restrict__ A = args.A[z];
  const short* __restrict__ W = args.W[z];
  const float* __restrict__ bias = args.b[z];
  short* __restrict__ Cout = args.out[z];

  const int m0 = blockIdx.x * 128;   // s
  const int n0 = blockIdx.y * 128;   // feat
  const int tid = threadIdx.x;
  const int wave = tid >> 6, lane = tid & 63;
  const int l32 = lane & 31, half = lane >> 5;
  const int wrow = (wave >> 1) * 64;
  const int wcol = (wave & 1) * 64;
  const int lxor = (l32 & 7) ^ ((l32 >> 3) & 3);

  __shared__ short Am[128][64];  // [s][k], swizzled, unpadded
  __shared__ short Wm[128][64];  // [feat][k], swizzled, unpadded

  f32x16 acc[2][2];
#pragma unroll
  for (int mb = 0; mb < 2; mb++)
#pragma unroll
    for (int nb = 0; nb < 2; nb++) acc[mb][nb] = (f32x16)0.f;

  for (int k0 = 0; k0 < GK; k0 += 64) {
    __syncthreads();
#pragma unroll
    for (int i = 0; i < 4; i++) {
      int f = wave * 256 + i * 64 + lane;
      int row = f >> 3, col = f & 7;
      int ksw = k0 + swz(row, col);
      gld16(A + (size_t)(m0 + row) * GK + ksw,
            (short*)Am + (size_t)(wave * 256 + i * 64) * 8);
      gld16(W + (size_t)(n0 + row) * GK + ksw,
            (short*)Wm + (size_t)(wave * 256 + i * 64) * 8);
    }
    __syncthreads();
#pragma unroll
    for (int c = 0; c < 4; c++) {
      const int sw = ((2 * c + half) ^ lxor) << 3;
      short8 af[2], bf[2];
#pragma unroll
      for (int mb = 0; mb < 2; mb++) {
        af[mb] = *(const short8*)(&Am[wrow + mb * 32 + l32][0] + sw);
        bf[mb] = *(const short8*)(&Wm[wcol + mb * 32 + l32][0] + sw);
      }
#pragma unroll
      for (int mb = 0; mb < 2; mb++)
#pragma unroll
        for (int nb = 0; nb < 2; nb++)
          acc[mb][nb] = __builtin_amdgcn_mfma_f32_32x32x16_bf16(
              af[mb], bf[nb], acc[mb][nb], 0, 0, 0);
    }
  }

  // Epilogue. C/D: n(lane)=feat, m(regs)=s. Coalesced along feat.
  const float sc = (z == 0) ? QSCALE : 1.0f;
  const int bb = m0 >> 11;
#pragma unroll
  for (int nb = 0; nb < 2; nb++) {
    const int n = n0 + wcol + nb * 32 + l32;
    const float bv = bias[n];
    const int h = n >> 6, d = n & 63;
#pragma unroll
    for (int mb = 0; mb < 2; mb++) {
      const int mbase = m0 + wrow + mb * 32 + 4 * half;
      if (z == 2) {
        // V^T scatter to [B*H][DH][S]; regs 4g..4g+3 = consecutive s
#pragma unroll
        for (int g = 0; g < 4; g++) {
          const int s = (mbase + g * 8) & 2047;
          short2 o0 = pk2bf(acc[mb][nb][4 * g + 0] + bv,
                            acc[mb][nb][4 * g + 1] + bv);
          short2 o1 = pk2bf(acc[mb][nb][4 * g + 2] + bv,
                            acc[mb][nb][4 * g + 3] + bv);
          short4 o = {o0.x, o0.y, o1.x, o1.y};
          *(short4*)&Cout[((size_t)(bb * 16 + h) * 64 + d) * 2048 + s] = o;
        }
      } else {
#pragma unroll
        for (int g = 0; g < 4; g++)
#pragma unroll
          for (int r = 0; r < 4; r++) {
            const int s = (mbase + g * 8 + r) & 2047;
            Cout[((size_t)(bb * 16 + h) * 2048 + s) * 64 + d] =
                f2bf((acc[mb][nb][4 * g + r] + bv) * sc);
          }
      }
    }
  }
}

// ---------------------------------------------------------------------------
// O-projection GEMM, BK=128: 16 MFMA/wave/iter (was 8), 16 barriers (was
// 32) — fixes the thin MFMA-per-staging-round imbalance. LDS 48 KB,
// grid (32,16) = 512 = 2 blocks/CU. fp32 out, coalesced along feat.
// ---------------------------------------------------------------------------
__global__ __launch_bounds__(256) void gemm_o(
    const short* __restrict__ A, const short* __restrict__ W,
    const float* __restrict__ bias, float* __restrict__ Cout) {
  const int m0 = blockIdx.x * 128;  // s
  const int n0 = blockIdx.y * 64;   // feat
  const int tid = threadIdx.x;
  const int wave = tid >> 6, lane = tid & 63;
  const int l32 = lane & 31, half = lane >> 5;
  const int lxor = (l32 & 7) ^ ((l32 >> 3) & 3);

  __shared__ short Am[128][128];  // [s][k], swizzled (32 KB)
  __shared__ short Wm[64][128];   // [feat][k], swizzled (16 KB)

  f32x16 acc[2];
  acc[0] = (f32x16)0.f;
  acc[1] = (f32x16)0.f;

  for (int k0 = 0; k0 < GK; k0 += 128) {
    __syncthreads();
    // A: 128 rows x 16 chunks = 2048 chunks -> 8 per thread
#pragma unroll
    for (int i = 0; i < 8; i++) {
      int f = tid + i * 256;
      int row = f >> 4, col = f & 15;
      gld16(A + (size_t)(m0 + row) * GK + k0 + swz(row, col),
            (short*)Am + (size_t)(wave * 64 + i * 256) * 8);
    }
    // W: 64 rows x 16 chunks = 1024 chunks -> 4 per thread
#pragma unroll
    for (int i = 0; i < 4; i++) {
      int f = tid + i * 256;
      int row = f >> 4, col = f & 15;
      gld16(W + (size_t)(n0 + row) * GK + k0 + swz(row, col),
            (short*)Wm + (size_t)(wave * 64 + i * 256) * 8);
    }
    __syncthreads();
#pragma unroll
    for (int c = 0; c < 8; c++) {
      const int sw = ((2 * c + half) ^ lxor) << 3;
      short8 af = *(const short8*)(&Am[wave * 32 + l32][0] + sw);
      short8 bf[2];
#pragma unroll
      for (int nb = 0; nb < 2; nb++)
        bf[nb] = *(const short8*)(&Wm[nb * 32 + l32][0] + sw);
#pragma unroll
      for (int nb = 0; nb < 2; nb++)
        acc[nb] = __builtin_amdgcn_mfma_f32_32x32x16_bf16(
            af, bf[nb], acc[nb], 0, 0, 0);
    }
  }

  // n(lane)=feat -> coalesced scalar stores
#pragma unroll
  for (int nb = 0; nb < 2; nb++) {
    const int n = n0 + nb * 32 + l32;
    const float bv = bias[n];
    const int mbase = m0 + wave * 32 + 4 * half;
#pragma unroll
    for (int g = 0; g < 4; g++)
#pragma unroll
      for (int r = 0; r < 4; r++)
        Cout[(size_t)(mbase + g * 8 + r) * DD + n] = acc[nb][4 * g + r] + bv;
  }
}

// ---------------------------------------------------------------------------
// Flash attention (round-8 math, restructured schedule): kt-loop unrolled
// by 2 so the LDS buffer index `cur` is a compile-time constant (constant
// LDS bases -> immediate offsets, hoisted addresses), and the 4 global
// staging pointers are strength-reduced registers (+8192 B K, +128 B V per
// kt) instead of per-kt 64-bit mad chains. Bit-identical arithmetic.
// ---------------------------------------------------------------------------
__global__ __launch_bounds__(256) void flash_mfma(
    const short* __restrict__ qh, const short* __restrict__ kh,
    const short* __restrict__ vt, short* __restrict__ ao) {
  const int bh = blockIdx.y;
  const int q0 = blockIdx.x * 128;
  const int tid = threadIdx.x;
  const int wave = tid >> 6, lane = tid & 63;
  const int l32 = lane & 31, half = lane >> 5;
  const int lxor = (l32 & 7) ^ ((l32 >> 3) & 3);

  __shared__ short Ks[2][64][64];   // [kk][d], swizzled
  __shared__ short Vs[2][64][64];   // [d][kk], swizzled
  __shared__ short Ps[4][32][68];   // per-wave [q][kk], pad 68 (2-way max)

  // Q B-fragments from global: q = l32, chunk c: d = c*16 + half*8
  short8 qf[4];
#pragma unroll
  for (int c = 0; c < 4; c++)
    qf[c] = *(const short8*)(
        qh + ((size_t)bh * SS + q0 + wave * 32 + l32) * 64 + c * 16 + half * 8);

  f32x16 o[2];
  o[0] = (f32x16)0.f;
  o[1] = (f32x16)0.f;
  float l_part = 0.f;

  // Strength-reduced staging pointers (this thread's two K + two V chunks)
  const int f0 = wave * 128 + lane, f1 = f0 + 64;
  const int r0 = f0 >> 3, c0 = f0 & 7;
  const int r1 = f1 >> 3, c1 = f1 & 7;
  const short* kp0 = kh + ((size_t)bh * SS + r0) * 64 + swz(r0, c0);
  const short* kp1 = kh + ((size_t)bh * SS + r1) * 64 + swz(r1, c1);
  const short* vp0 = vt + ((size_t)bh * 64 + r0) * SS + swz(r0, c0);
  const short* vp1 = vt + ((size_t)bh * 64 + r1) * SS + swz(r1, c1);

  auto prefetch = [&](const int buf) {
    gld16(kp0, (short*)Ks + (size_t)buf * 4096 + (size_t)(wave * 128) * 8);
    gld16(kp1, (short*)Ks + (size_t)buf * 4096 + (size_t)(wave * 128 + 64) * 8);
    gld16(vp0, (short*)Vs + (size_t)buf * 4096 + (size_t)(wave * 128) * 8);
    gld16(vp1, (short*)Vs + (size_t)buf * 4096 + (size_t)(wave * 128 + 64) * 8);
    kp0 += 4096; kp1 += 4096;  // next K tile: +64 rows * 64 shorts
    vp0 += 64;   vp1 += 64;    // next V tile: +64 columns
  };

  prefetch(0);
  __syncthreads();

  auto body = [&](const int cur, const bool pf) {
    if (pf) prefetch(1 - cur);  // async, drained by the end-of-body barrier

    // S^T = K · Q^T : m = kk (2 blocks), n = q
    f32x16 s[2];
    s[0] = (f32x16)0.f;
    s[1] = (f32x16)0.f;
#pragma unroll
    for (int c = 0; c < 4; c++) {
      const int sw = ((2 * c + half) ^ lxor) << 3;
      short8 kf[2];
#pragma unroll
      for (int mb = 0; mb < 2; mb++)
        kf[mb] = *(const short8*)(&Ks[cur][mb * 32 + l32][0] + sw);
#pragma unroll
      for (int mb = 0; mb < 2; mb++)
        s[mb] = __builtin_amdgcn_mfma_f32_32x32x16_bf16(
            kf[mb], qf[c], s[mb], 0, 0, 0);
    }

    // p = exp2(s); per-lane partial l via register pairwise tree
#pragma unroll
    for (int mb = 0; mb < 2; mb++)
#pragma unroll
      for (int r = 0; r < 16; r++)
        s[mb][r] = __builtin_amdgcn_exp2f(s[mb][r]);
    {
      float t[16];
#pragma unroll
      for (int r = 0; r < 16; r++) t[r] = s[0][r] + s[1][r];
#pragma unroll
      for (int st = 8; st > 0; st >>= 1)
#pragma unroll
        for (int r = 0; r < st; r++) t[r] += t[r + st];
      l_part += t[0];
    }

    // P^T -> wave-private LDS [q][kk]; regs 4g..4g+3 = consecutive kk
#pragma unroll
    for (int mb = 0; mb < 2; mb++)
#pragma unroll
      for (int g = 0; g < 4; g++) {
        short2 p0 = pk2bf(s[mb][4 * g + 0], s[mb][4 * g + 1]);
        short2 p1 = pk2bf(s[mb][4 * g + 2], s[mb][4 * g + 3]);
        short4 pk = {p0.x, p0.y, p1.x, p1.y};
        *(short4*)&Ps[wave][l32][mb * 32 + g * 8 + half * 4] = pk;
      }

    // O^T += V^T · P^T : m = d (2 blocks), n = q, k = kk
#pragma unroll
    for (int c = 0; c < 4; c++) {
      const int sw = ((2 * c + half) ^ lxor) << 3;
      short8 vf[2];
#pragma unroll
      for (int mb = 0; mb < 2; mb++)
        vf[mb] = *(const short8*)(&Vs[cur][mb * 32 + l32][0] + sw);
      short8 pf2 = *(const short8*)&Ps[wave][l32][c * 16 + half * 8];
#pragma unroll
      for (int mb = 0; mb < 2; mb++)
        o[mb] = __builtin_amdgcn_mfma_f32_32x32x16_bf16(
            vf[mb], pf2, o[mb], 0, 0, 0);
    }

    __syncthreads();  // drains prefetch + guards buffer swap
  };

#pragma unroll 1
  for (int t = 0; t < 16; t++) {
    body(0, true);       // kt = 2t,   prefetch kt+1 into buf 1
    body(1, t != 15);    // kt = 2t+1, prefetch kt+1 into buf 0
  }

  // Epilogue: l across halves via one shuffle; O^T n=q, m=d.
  const float l_tot = l_part + __shfl_xor(l_part, 32);
  const float inv = 1.0f / l_tot;
  const int b = bh >> 4, h = bh & 15;
  const int q = q0 + wave * 32 + l32;
#pragma unroll
  for (int mb = 0; mb < 2; mb++)
#pragma unroll
    for (int g = 0; g < 4; g++) {
      const int d = mb * 32 + g * 8 + half * 4;
      short2 o0 = pk2bf(o[mb][4 * g + 0] * inv, o[mb][4 * g + 1] * inv);
      short2 o1 = pk2bf(o[mb][4 * g + 2] * inv, o[mb][4 * g + 3] * inv);
      short4 ok = {o0.x, o0.y, o1.x, o1.y};
      *(short4*)&ao[((size_t)b * SS + q) * DD + h * 64 + d] = ok;
    }
}

// ---------------------------------------------------------------------------
extern "C" void kernel_launch(void* const* d_in, const int* in_sizes, int n_in,
                              void* d_out, int out_size, void* d_ws,
                              size_t ws_size, hipStream_t stream) {
  const float* q = (const float*)d_in[0];
  const float* k = (const float*)d_in[1];
  const float* v = (const float*)d_in[2];
  const float* Wq = (const float*)d_in[3];
  const float* bq = (const float*)d_in[4];
  const float* Wk = (const float*)d_in[5];
  const float* bk = (const float*)d_in[6];
  const float* Wv = (const float*)d_in[7];
  const float* bv = (const float*)d_in[8];
  const float* Wo = (const float*)d_in[9];
  const float* bo = (const float*)d_in[10];
  float* out = (float*)d_out;

  const size_t MEG = 1024 * 1024;
  short* wsb = (short*)d_ws;
  short* Wqb = wsb + 0 * MEG;
  short* Wkb = wsb + 1 * MEG;
  short* Wvb = wsb + 2 * MEG;
  short* Wob = wsb + 3 * MEG;
  short* qb = wsb + 4 * MEG;    // bf16 copies of q,k,v: 4M each
  short* kb = wsb + 8 * MEG;
  short* vb = wsb + 12 * MEG;
  short* qhp = wsb + 16 * MEG;  // [B*H][S][DH] (pre-scaled by log2e/8)
  short* khp = wsb + 20 * MEG;  // [B*H][S][DH]
  short* vtp = wsb + 24 * MEG;  // [B*H][DH][S]
  short* aop = wsb + 28 * MEG;  // [B,S,D]

  CvtArgs ca;
  ca.s[0] = q;  ca.d[0] = qb;  ca.n8[0] = 524288;
  ca.s[1] = k;  ca.d[1] = kb;  ca.n8[1] = 524288;
  ca.s[2] = v;  ca.d[2] = vb;  ca.n8[2] = 524288;
  ca.s[3] = Wq; ca.d[3] = Wqb; ca.n8[3] = 131072;
  ca.s[4] = Wk; ca.d[4] = Wkb; ca.n8[4] = 131072;
  ca.s[5] = Wv; ca.d[5] = Wvb; ca.n8[5] = 131072;
  ca.s[6] = Wo; ca.d[6] = Wob; ca.n8[6] = 131072;
  cvt_all<<<dim3(2048, 7), 256, 0, stream>>>(ca);

  QkvArgs qa;
  qa.A[0] = qb; qa.W[0] = Wqb; qa.b[0] = bq; qa.out[0] = qhp;
  qa.A[1] = kb; qa.W[1] = Wkb; qa.b[1] = bk; qa.out[1] = khp;
  qa.A[2] = vb; qa.W[2] = Wvb; qa.b[2] = bv; qa.out[2] = vtp;
  qkv_gemm<<<dim3(GM / 128, DD / 128, 3), 256, 0, stream>>>(qa);

  flash_mfma<<<dim3(SS / 128, 32), 256, 0, stream>>>(qhp, khp, vtp, aop);

  gemm_o<<<dim3(GM / 128, DD / 64), 256, 0, stream>>>(aop, Wob, bo, out);
}